// Round 17
// baseline (54.579 us; speedup 1.0000x reference)
//
#include <hip/hip_runtime.h>
#include <math.h>

#define EPS_GMO  1e-16f
#define EPS_BARY 1e-16f
#define EPS_DIV  1e-12f
#define TPB  512
#define RTPB 256
#define NWAVE (TPB / 64)
#define GPTS 8
#define FSTRIDE 12
#define QCAP 2048

// ---------------------------------------------------------------------------
// Kernel 1: per-face constants: a(3), ab(3), ac(3), saa, sab, scc (12 floats).
// ---------------------------------------------------------------------------
__global__ void gather_fdat_kernel(const float* __restrict__ verts,
                                   const int* __restrict__ faces,
                                   float* __restrict__ fdat,
                                   int B, int F, int V)
{
    int i = blockIdx.x * blockDim.x + threadIdx.x;
    if (i >= B * F) return;
    int b = i / F;
    int f = i - b * F;
    int i0 = faces[f * 3 + 0], i1 = faces[f * 3 + 1], i2 = faces[f * 3 + 2];
    const float* pa = verts + ((size_t)b * V + i0) * 3;
    const float* pb = verts + ((size_t)b * V + i1) * 3;
    const float* pc = verts + ((size_t)b * V + i2) * 3;
    float ax = pa[0], ay = pa[1], az = pa[2];
    float abx = pb[0] - ax, aby = pb[1] - ay, abz = pb[2] - az;
    float acx = pc[0] - ax, acy = pc[1] - ay, acz = pc[2] - az;
    float saa = abx * abx + aby * aby + abz * abz;
    float sab = abx * acx + aby * acy + abz * acz;
    float scc = acx * acx + acy * acy + acz * acz;
    float* o = fdat + (size_t)i * FSTRIDE;
    o[0] = ax;  o[1] = ay;  o[2] = az;
    o[3] = abx; o[4] = aby; o[5] = abz;
    o[6] = acx; o[7] = acy; o[8] = acz;
    o[9] = saa; o[10] = sab; o[11] = scc;
}

// ---------------------------------------------------------------------------
// Exact squared point-triangle distance — BITWISE mirror of the reference
// (validated absmax 0.0 rounds 1/2/5/6/8-12/14-16). Used only on candidates.
// ---------------------------------------------------------------------------
__device__ float tri_sqdist_exact(float px, float py, float pz,
                                  float ax, float ay, float az,
                                  float bx, float by, float bz,
                                  float cx, float cy, float cz)
{
#pragma clang fp contract(off)
    float abx = bx - ax, aby = by - ay, abz = bz - az;
    float acx = cx - ax, acy = cy - ay, acz = cz - az;
    float apx = px - ax, apy = py - ay, apz = pz - az;
    float d1 = abx * apx + aby * apy + abz * apz;
    float d2 = acx * apx + acy * apy + acz * apz;
    float bpx = px - bx, bpy = py - by, bpz = pz - bz;
    float d3 = abx * bpx + aby * bpy + abz * bpz;
    float d4 = acx * bpx + acy * bpy + acz * bpz;
    float cpx_ = px - cx, cpy_ = py - cy, cpz_ = pz - cz;
    float d5 = abx * cpx_ + aby * cpy_ + abz * cpz_;
    float d6 = acx * cpx_ + acy * cpy_ + acz * cpz_;
    float va = d3 * d6 - d5 * d4;
    float vb = d5 * d2 - d1 * d6;
    float vc = d1 * d4 - d3 * d2;
    float t_ab = d1 / fmaxf(d1 - d3, EPS_DIV);
    float t_ac = d2 / fmaxf(d2 - d6, EPS_DIV);
    float t_bc = (d4 - d3) / fmaxf((d4 - d3) + (d5 - d6), EPS_DIV);
    float den = fmaxf(va + vb + vc, EPS_DIV);
    float v = vb / den;
    float w = vc / den;
    float qx = ax + v * abx + w * acx;
    float qy = ay + v * aby + w * acy;
    float qz = az + v * abz + w * acz;
    bool m_bc = (va <= 0.0f) && (d4 - d3 >= 0.0f) && (d5 - d6 >= 0.0f);
    bool m_ac = (vb <= 0.0f) && (d2 >= 0.0f) && (d6 <= 0.0f);
    bool m_ab = (vc <= 0.0f) && (d1 >= 0.0f) && (d3 <= 0.0f);
    bool m_a  = (d1 <= 0.0f) && (d2 <= 0.0f);
    bool m_b  = (d3 >= 0.0f) && (d4 <= d3);
    bool m_c  = (d6 >= 0.0f) && (d5 <= d6);
    if (m_bc) { qx = bx + t_bc * (cx - bx); qy = by + t_bc * (cy - by); qz = bz + t_bc * (cz - bz); }
    if (m_ac) { qx = ax + t_ac * acx;       qy = ay + t_ac * acy;       qz = az + t_ac * acz; }
    if (m_ab) { qx = ax + t_ab * abx;       qy = ay + t_ab * aby;       qz = az + t_ab * abz; }
    if (m_c)  { qx = cx; qy = cy; qz = cz; }
    if (m_b)  { qx = bx; qy = by; qz = bz; }
    if (m_a)  { qx = ax; qy = ay; qz = az; }
    float dx = px - qx, dy = py - qy, dz = pz - qz;
    return dx * dx + dy * dy + dz * dz;
}

// u8 code: monotone floor of d (exponent + 2 mantissa bits), so
// d <= T  ==>  code(d) <= code(T). Candidate set only inflates (~1.19x).
__device__ __forceinline__ int dcode(float d)
{
    unsigned raw = __float_as_uint(d) >> 21;
    int c = (int)raw - 380;
    return c < 0 ? 0 : (c > 255 ? 255 : c);
}

// ---------------------------------------------------------------------------
// Main kernel: R16 base, GPTS 4->8 (single-variable change). Per-face loads,
// rcp setup, and code-pack amortize over 8 evals; pass-2a scan halves.
// Grid 512 = 2 blocks/CU = 16 waves/CU (R9-proven sufficient occupancy).
// ---------------------------------------------------------------------------
__global__ __launch_bounds__(TPB) void p2s_main_kernel(
    const float* __restrict__ points,
    const float* __restrict__ verts,
    const int* __restrict__ faces,
    const float* __restrict__ fdat,
    float* __restrict__ robust_out,
    int P, int V, int F, int npts)
{
    extern __shared__ unsigned dstore32[];       // [F][2]: 8x u8 codes per face
    __shared__ float swmin[NWAVE][GPTS];
    __shared__ float sargd[NWAVE][GPTS];
    __shared__ int   sargi[NWAVE][GPTS];
    __shared__ unsigned squeue[QCAP];
    __shared__ unsigned scnt;

    const int tid  = threadIdx.x;
    const int lane = tid & 63;
    const int wid  = tid >> 6;
    const int gp0  = blockIdx.x * GPTS;
    const int b    = gp0 / P;   // P % GPTS == 0, block never straddles batches

    if (tid == 0) scnt = 0;

    float px[GPTS], py[GPTS], pz[GPTS];
#pragma unroll
    for (int g = 0; g < GPTS; ++g) {
        int gp = gp0 + g; if (gp >= npts) gp = npts - 1;
        const float* pp = points + (size_t)gp * 3;
        px[g] = pp[0]; py[g] = pp[1]; pz[g] = pp[2];
    }

    const float* fb = fdat + (size_t)b * F * FSTRIDE;

    // ---------------- pass 1: cheap exact screen ----------------
    float best[GPTS];
#pragma unroll
    for (int g = 0; g < GPTS; ++g) best[g] = INFINITY;

    for (int f = tid; f < F; f += TPB) {
        const float* fd = fb + (size_t)f * FSTRIDE;
        float4 q0 = *(const float4*)(fd + 0);
        float4 q1 = *(const float4*)(fd + 4);
        float4 q2 = *(const float4*)(fd + 8);
        float ax = q0.x, ay = q0.y, az = q0.z;
        float abx = q0.w, aby = q1.x, abz = q1.y;
        float acx = q1.z, acy = q1.w, acz = q2.x;
        float saa = q2.y, sab = q2.z, scc = q2.w;
        float cbb = saa - 2.0f * sab + scc;
        float det = saa * scc - sab * sab;
        float rsaa = __builtin_amdgcn_rcpf(fmaxf(saa, 1e-30f));
        float rscc = __builtin_amdgcn_rcpf(fmaxf(scc, 1e-30f));
        float rcbb = __builtin_amdgcn_rcpf(fmaxf(cbb, 1e-30f));
        float rdet = __builtin_amdgcn_rcpf(fmaxf(det, 1e-30f));
        float k1 = saa - sab;
        unsigned w0 = 0, w1 = 0;
#pragma unroll
        for (int g = 0; g < GPTS; ++g) {
            float apx = px[g] - ax, apy = py[g] - ay, apz = pz[g] - az;
            float sap = apx * apx + apy * apy + apz * apz;
            float d1 = apx * abx + apy * aby + apz * abz;
            float d2 = apx * acx + apy * acy + apz * acz;
            float t0 = __builtin_amdgcn_fmed3f(d1 * rsaa, 0.0f, 1.0f);
            float h0 = d1 + d1;
            float dab = sap - t0 * (h0 - t0 * saa);
            float t1 = __builtin_amdgcn_fmed3f(d2 * rscc, 0.0f, 1.0f);
            float dac = sap - t1 * ((d2 + d2) - t1 * scc);
            float e1 = (d2 - d1) + k1;
            float t2 = __builtin_amdgcn_fmed3f(e1 * rcbb, 0.0f, 1.0f);
            float bpp = (sap - h0) + saa;
            float dbc = bpp - t2 * ((e1 + e1) - t2 * cbb);
            float dmin = fminf(fminf(dab, dac), dbc);
            float vnum = scc * d1 - sab * d2;
            float wnum = saa * d2 - sab * d1;
            bool inside = (vnum >= 0.0f) & (wnum >= 0.0f) & ((vnum + wnum) <= det);
            float idist = sap - (vnum * d1 + wnum * d2) * rdet;
            float d = fmaxf(inside ? fminf(idist, dmin) : dmin, 0.0f);
            unsigned code = (unsigned)dcode(d);
            if (g < 4) w0 |= code << (8 * g);
            else       w1 |= code << (8 * (g - 4));
            best[g] = fminf(best[g], d);
        }
        *(uint2*)&dstore32[(size_t)f * 2] = make_uint2(w0, w1);
    }

    // ---------------- min reduction: shfl butterfly + 1 barrier --------------
#pragma unroll
    for (int m = 1; m < 64; m <<= 1) {
#pragma unroll
        for (int g = 0; g < GPTS; ++g)
            best[g] = fminf(best[g], __shfl_xor(best[g], m));
    }
    if (lane == 0) {
#pragma unroll
        for (int g = 0; g < GPTS; ++g) swmin[wid][g] = best[g];
    }
    __syncthreads();   // orders dstore32 writes + scnt=0 before pass 2a

    float Tg[GPTS]; int codeT[GPTS];
#pragma unroll
    for (int g = 0; g < GPTS; ++g) {
        float mn = swmin[0][g];
#pragma unroll
        for (int w = 1; w < NWAVE; ++w) mn = fminf(mn, swmin[w][g]);
        Tg[g] = mn + (1e-4f + 1e-2f * mn);   // proven band (R9-R16)
        codeT[g] = dcode(Tg[g]);
    }

    // ---------------- pass 2a: scan codes, compact candidates ----------------
    for (int f = tid; f < F; f += TPB) {
        uint2 wv = *(const uint2*)&dstore32[(size_t)f * 2];
#pragma unroll
        for (int g = 0; g < GPTS; ++g) {
            unsigned code = (g < 4) ? ((wv.x >> (8 * g)) & 0xffu)
                                    : ((wv.y >> (8 * (g - 4))) & 0xffu);
            if ((int)code <= codeT[g]) {
                unsigned idx = atomicAdd(&scnt, 1u);
                if (idx < QCAP) squeue[idx] = ((unsigned)g << 13) | (unsigned)f;
            }
        }
    }
    __syncthreads();
    unsigned total = scnt;

    float bestE[GPTS]; int bestI[GPTS];
#pragma unroll
    for (int g = 0; g < GPTS; ++g) { bestE[g] = INFINITY; bestI[g] = 0x7fffffff; }

    if (total <= QCAP) {
        // ---------------- pass 2b: dense exact evals over queue ----------------
        for (unsigned q = tid; q < total; q += TPB) {
            unsigned e = squeue[q];
            int g = (int)(e >> 13);
            int f = (int)(e & 0x1fffu);
            int i0 = faces[f * 3 + 0], i1 = faces[f * 3 + 1], i2 = faces[f * 3 + 2];
            const float* pa = verts + ((size_t)b * V + i0) * 3;
            const float* pbv = verts + ((size_t)b * V + i1) * 3;
            const float* pc = verts + ((size_t)b * V + i2) * 3;
            float de = tri_sqdist_exact(px[g], py[g], pz[g],
                                        pa[0], pa[1], pa[2],
                                        pbv[0], pbv[1], pbv[2],
                                        pc[0], pc[1], pc[2]);
            if (de < bestE[g] || (de == bestE[g] && f < bestI[g])) {
                bestE[g] = de; bestI[g] = f;
            }
        }
    } else {
        // ---------------- overflow fallback: in-branch rescan (proven) --------
        for (int f = tid; f < F; f += TPB) {
            uint2 wv = *(const uint2*)&dstore32[(size_t)f * 2];
            bool cg[GPTS]; bool any = false;
#pragma unroll
            for (int g = 0; g < GPTS; ++g) {
                unsigned code = (g < 4) ? ((wv.x >> (8 * g)) & 0xffu)
                                        : ((wv.y >> (8 * (g - 4))) & 0xffu);
                cg[g] = (int)code <= codeT[g];
                any = any || cg[g];
            }
            if (any) {
                int i0 = faces[f * 3 + 0], i1 = faces[f * 3 + 1], i2 = faces[f * 3 + 2];
                const float* pa = verts + ((size_t)b * V + i0) * 3;
                const float* pbv = verts + ((size_t)b * V + i1) * 3;
                const float* pc = verts + ((size_t)b * V + i2) * 3;
                float ax = pa[0], ay = pa[1], az = pa[2];
                float bx = pbv[0], by = pbv[1], bz = pbv[2];
                float cx = pc[0], cy = pc[1], cz = pc[2];
#pragma unroll
                for (int g = 0; g < GPTS; ++g) {
                    if (cg[g]) {
                        float de = tri_sqdist_exact(px[g], py[g], pz[g],
                                                    ax, ay, az, bx, by, bz, cx, cy, cz);
                        if (de < bestE[g]) { bestE[g] = de; bestI[g] = f; }
                    }
                }
            }
        }
    }

    // ---------------- argmin: paired 32-bit shfl butterfly + 1 barrier --------
#pragma unroll
    for (int m = 1; m < 64; m <<= 1) {
#pragma unroll
        for (int g = 0; g < GPTS; ++g) {
            float od = __shfl_xor(bestE[g], m);
            int   oi = __shfl_xor(bestI[g], m);
            if (od < bestE[g] || (od == bestE[g] && oi < bestI[g])) {
                bestE[g] = od; bestI[g] = oi;
            }
        }
    }
    if (lane == 0) {
#pragma unroll
        for (int g = 0; g < GPTS; ++g) { sargd[wid][g] = bestE[g]; sargi[wid][g] = bestI[g]; }
    }
    __syncthreads();

    // ---------------- final: merge waves + exact barycentric + GMO (mirror) --
    if (tid < GPTS) {
#pragma clang fp contract(off)
        int g = tid;
        float dmn = sargd[0][g]; int imn = sargi[0][g];
#pragma unroll
        for (int w = 1; w < NWAVE; ++w) {
            float dv = sargd[w][g]; int iv = sargi[w][g];
            if (dv < dmn || (dv == dmn && iv < imn)) { dmn = dv; imn = iv; }
        }
        int f = imn;
        int gp = gp0 + g;
        if (gp < npts) {
            int i0 = faces[f * 3 + 0], i1 = faces[f * 3 + 1], i2 = faces[f * 3 + 2];
            const float* pa = verts + ((size_t)b * V + i0) * 3;
            const float* pbv = verts + ((size_t)b * V + i1) * 3;
            const float* pc = verts + ((size_t)b * V + i2) * 3;
            float ax = pa[0], ay = pa[1], az = pa[2];
            float bx = pbv[0], by = pbv[1], bz = pbv[2];
            float cx = pc[0], cy = pc[1], cz = pc[2];
            float Px = px[g], Py = py[g], Pz = pz[g];
            float v1x = bx - ax, v1y = by - ay, v1z = bz - az;
            float v2x = cx - ax, v2y = cy - ay, v2z = cz - az;
            float nx = v1y * v2z - v1z * v2y;
            float ny = v1z * v2x - v1x * v2z;
            float nz = v1x * v2y - v1y * v2x;
            float nn = nx * nx + ny * ny + nz * nz;
            if (nn < EPS_BARY) nn = 1.0f;
            float wx = Px - ax, wy = Py - ay, wz = Pz - az;
            float c1x = v1y * wz - v1z * wy;
            float c1y = v1z * wx - v1x * wz;
            float c1z = v1x * wy - v1y * wx;
            float gamma = (c1x * nx + c1y * ny + c1z * nz) / nn;
            float c2x = wy * v2z - wz * v2y;
            float c2y = wz * v2x - wx * v2z;
            float c2z = wx * v2y - wy * v2x;
            float beta = (c2x * nx + c2y * ny + c2z * nz) / nn;
            float alpha = 1.0f - beta - gamma;
            float cpx = ax * alpha + bx * beta + cx * gamma;
            float cpy = ay * alpha + by * beta + cy * gamma;
            float cpz = az * alpha + bz * beta + cz * gamma;
            float dx = cpx - Px, dy = cpy - Py, dz = cpz - Pz;
            float sdist = dx * dx + dy * dy + dz * dz;
            float r = sqrtf(sdist / (1.0f + sdist) + EPS_GMO);
            robust_out[gp] = r;
        }
    }
}

// ---------------------------------------------------------------------------
// Kernel 3: deterministic fixed-order mean of N values -> out[0]
// ---------------------------------------------------------------------------
__global__ __launch_bounds__(RTPB) void reduce_mean_kernel(
    const float* __restrict__ vals, float* __restrict__ out, int N, float inv)
{
    __shared__ float s[RTPB];
    int tid = threadIdx.x;
    float acc = 0.0f;
    for (int i = tid; i < N; i += RTPB) acc += vals[i];
    s[tid] = acc;
    __syncthreads();
    for (int st = RTPB / 2; st > 0; st >>= 1) {
        if (tid < st) s[tid] += s[tid + st];
        __syncthreads();
    }
    if (tid == 0) out[0] = s[0] * inv;
}

// ---------------------------------------------------------------------------
extern "C" void kernel_launch(void* const* d_in, const int* in_sizes, int n_in,
                              void* d_out, int out_size, void* d_ws, size_t ws_size,
                              hipStream_t stream)
{
    const float* points = (const float*)d_in[0];
    const float* verts  = (const float*)d_in[1];
    const int*   faces  = (const int*)d_in[2];
    float* out = (float*)d_out;

    const int B = 2;  // fixed by the reference setup
    const int P = in_sizes[0] / (B * 3);
    const int V = in_sizes[1] / (B * 3);
    const int F = in_sizes[2] / 3;
    const int npts = B * P;

    // ws layout (507,904 B total -- proven in rounds 2/5/8-12/14-16):
    float* fdat   = (float*)d_ws;                    // B*F*12 floats
    float* robust = fdat + (size_t)B * F * FSTRIDE;  // npts floats

    int nBF = B * F;
    gather_fdat_kernel<<<(nBF + RTPB - 1) / RTPB, RTPB, 0, stream>>>(verts, faces, fdat, B, F, V);

    int nBlocks = (npts + GPTS - 1) / GPTS;          // 512 blocks of 512 thr
    size_t dynLds = (size_t)F * 2 * sizeof(unsigned); // 40,960 B
    p2s_main_kernel<<<nBlocks, TPB, dynLds, stream>>>(points, verts, faces, fdat, robust, P, V, F, npts);

    reduce_mean_kernel<<<1, RTPB, 0, stream>>>(robust, out, npts, 1.0f / (float)npts);
}

// Round 18
// 54.059 us; speedup vs baseline: 1.0096x; 1.0096x over previous
//
#include <hip/hip_runtime.h>
#include <math.h>

#define EPS_GMO  1e-16f
#define EPS_BARY 1e-16f
#define EPS_DIV  1e-12f
#define TPB  512
#define RTPB 256
#define NWAVE (TPB / 64)
#define GPTS 4
#define FSTRIDE 12
#define QCAP 2048

// ---------------------------------------------------------------------------
// Kernel 1: per-face constants: a(3), ab(3), ac(3), saa, sab, scc (12 floats).
// ---------------------------------------------------------------------------
__global__ void gather_fdat_kernel(const float* __restrict__ verts,
                                   const int* __restrict__ faces,
                                   float* __restrict__ fdat,
                                   int B, int F, int V)
{
    int i = blockIdx.x * blockDim.x + threadIdx.x;
    if (i >= B * F) return;
    int b = i / F;
    int f = i - b * F;
    int i0 = faces[f * 3 + 0], i1 = faces[f * 3 + 1], i2 = faces[f * 3 + 2];
    const float* pa = verts + ((size_t)b * V + i0) * 3;
    const float* pb = verts + ((size_t)b * V + i1) * 3;
    const float* pc = verts + ((size_t)b * V + i2) * 3;
    float ax = pa[0], ay = pa[1], az = pa[2];
    float abx = pb[0] - ax, aby = pb[1] - ay, abz = pb[2] - az;
    float acx = pc[0] - ax, acy = pc[1] - ay, acz = pc[2] - az;
    float saa = abx * abx + aby * aby + abz * abz;
    float sab = abx * acx + aby * acy + abz * acz;
    float scc = acx * acx + acy * acy + acz * acz;
    float* o = fdat + (size_t)i * FSTRIDE;
    o[0] = ax;  o[1] = ay;  o[2] = az;
    o[3] = abx; o[4] = aby; o[5] = abz;
    o[6] = acx; o[7] = acy; o[8] = acz;
    o[9] = saa; o[10] = sab; o[11] = scc;
}

// ---------------------------------------------------------------------------
// Exact squared point-triangle distance — BITWISE mirror of the reference
// (validated absmax 0.0 rounds 1/2/5/6/8-12/14-17). Used only on candidates.
// ---------------------------------------------------------------------------
__device__ float tri_sqdist_exact(float px, float py, float pz,
                                  float ax, float ay, float az,
                                  float bx, float by, float bz,
                                  float cx, float cy, float cz)
{
#pragma clang fp contract(off)
    float abx = bx - ax, aby = by - ay, abz = bz - az;
    float acx = cx - ax, acy = cy - ay, acz = cz - az;
    float apx = px - ax, apy = py - ay, apz = pz - az;
    float d1 = abx * apx + aby * apy + abz * apz;
    float d2 = acx * apx + acy * apy + acz * apz;
    float bpx = px - bx, bpy = py - by, bpz = pz - bz;
    float d3 = abx * bpx + aby * bpy + abz * bpz;
    float d4 = acx * bpx + acy * bpy + acz * bpz;
    float cpx_ = px - cx, cpy_ = py - cy, cpz_ = pz - cz;
    float d5 = abx * cpx_ + aby * cpy_ + abz * cpz_;
    float d6 = acx * cpx_ + acy * cpy_ + acz * cpz_;
    float va = d3 * d6 - d5 * d4;
    float vb = d5 * d2 - d1 * d6;
    float vc = d1 * d4 - d3 * d2;
    float t_ab = d1 / fmaxf(d1 - d3, EPS_DIV);
    float t_ac = d2 / fmaxf(d2 - d6, EPS_DIV);
    float t_bc = (d4 - d3) / fmaxf((d4 - d3) + (d5 - d6), EPS_DIV);
    float den = fmaxf(va + vb + vc, EPS_DIV);
    float v = vb / den;
    float w = vc / den;
    float qx = ax + v * abx + w * acx;
    float qy = ay + v * aby + w * acy;
    float qz = az + v * abz + w * acz;
    bool m_bc = (va <= 0.0f) && (d4 - d3 >= 0.0f) && (d5 - d6 >= 0.0f);
    bool m_ac = (vb <= 0.0f) && (d2 >= 0.0f) && (d6 <= 0.0f);
    bool m_ab = (vc <= 0.0f) && (d1 >= 0.0f) && (d3 <= 0.0f);
    bool m_a  = (d1 <= 0.0f) && (d2 <= 0.0f);
    bool m_b  = (d3 >= 0.0f) && (d4 <= d3);
    bool m_c  = (d6 >= 0.0f) && (d5 <= d6);
    if (m_bc) { qx = bx + t_bc * (cx - bx); qy = by + t_bc * (cy - by); qz = bz + t_bc * (cz - bz); }
    if (m_ac) { qx = ax + t_ac * acx;       qy = ay + t_ac * acy;       qz = az + t_ac * acz; }
    if (m_ab) { qx = ax + t_ab * abx;       qy = ay + t_ab * aby;       qz = az + t_ab * abz; }
    if (m_c)  { qx = cx; qy = cy; qz = cz; }
    if (m_b)  { qx = bx; qy = by; qz = bz; }
    if (m_a)  { qx = ax; qy = ay; qz = az; }
    float dx = px - qx, dy = py - qy, dz = pz - qz;
    return dx * dx + dy * dy + dz * dz;
}

// u8 code: monotone floor of d (exponent + 2 mantissa bits), so
// d <= T  ==>  code(d) <= code(T). Candidate set only inflates (~1.19x).
__device__ __forceinline__ int dcode(float d)
{
    unsigned raw = __float_as_uint(d) >> 21;
    int c = (int)raw - 380;
    return c < 0 ? 0 : (c > 255 ? 255 : c);
}

// ---------------------------------------------------------------------------
// Main kernel: R16 base (champion: 45.3 us main) + manual 2-stage software
// pipeline in pass 1 (next face's 3x float4 loads issued before current
// face's eval) to hide the L2 load latency under the ~350-cyc eval body.
// ---------------------------------------------------------------------------
__global__ __launch_bounds__(TPB) void p2s_main_kernel(
    const float* __restrict__ points,
    const float* __restrict__ verts,
    const int* __restrict__ faces,
    const float* __restrict__ fdat,
    float* __restrict__ robust_out,
    int P, int V, int F, int npts)
{
    extern __shared__ unsigned dstore32[];       // [F] 4x u8 codes per word
    __shared__ float swmin[NWAVE][GPTS];
    __shared__ float sargd[NWAVE][GPTS];
    __shared__ int   sargi[NWAVE][GPTS];
    __shared__ unsigned squeue[QCAP];
    __shared__ unsigned scnt;

    const int tid  = threadIdx.x;
    const int lane = tid & 63;
    const int wid  = tid >> 6;
    const int gp0  = blockIdx.x * GPTS;
    const int b    = gp0 / P;   // P % GPTS == 0, block never straddles batches

    if (tid == 0) scnt = 0;

    float px[GPTS], py[GPTS], pz[GPTS];
#pragma unroll
    for (int g = 0; g < GPTS; ++g) {
        int gp = gp0 + g; if (gp >= npts) gp = npts - 1;
        const float* pp = points + (size_t)gp * 3;
        px[g] = pp[0]; py[g] = pp[1]; pz[g] = pp[2];
    }

    const float* fb = fdat + (size_t)b * F * FSTRIDE;

    // ---------------- pass 1: screen with 2-stage load pipeline --------------
    float best[GPTS];
#pragma unroll
    for (int g = 0; g < GPTS; ++g) best[g] = INFINITY;

    // prologue: load face tid
    float4 q0, q1, q2;
    {
        const float* fd = fb + (size_t)tid * FSTRIDE;
        q0 = *(const float4*)(fd + 0);
        q1 = *(const float4*)(fd + 4);
        q2 = *(const float4*)(fd + 8);
    }

    for (int f = tid; f < F; f += TPB) {
        // issue next iteration's loads FIRST (latency hides under eval below)
        int fn = f + TPB;
        int fc = (fn < F) ? fn : tid;          // clamped safe address
        const float* fdn = fb + (size_t)fc * FSTRIDE;
        float4 n0 = *(const float4*)(fdn + 0);
        float4 n1 = *(const float4*)(fdn + 4);
        float4 n2 = *(const float4*)(fdn + 8);

        float ax = q0.x, ay = q0.y, az = q0.z;
        float abx = q0.w, aby = q1.x, abz = q1.y;
        float acx = q1.z, acy = q1.w, acz = q2.x;
        float saa = q2.y, sab = q2.z, scc = q2.w;
        float cbb = saa - 2.0f * sab + scc;
        float det = saa * scc - sab * sab;
        float rsaa = __builtin_amdgcn_rcpf(fmaxf(saa, 1e-30f));
        float rscc = __builtin_amdgcn_rcpf(fmaxf(scc, 1e-30f));
        float rcbb = __builtin_amdgcn_rcpf(fmaxf(cbb, 1e-30f));
        float rdet = __builtin_amdgcn_rcpf(fmaxf(det, 1e-30f));
        float k1 = saa - sab;
        unsigned wcode = 0;
#pragma unroll
        for (int g = 0; g < GPTS; ++g) {
            float apx = px[g] - ax, apy = py[g] - ay, apz = pz[g] - az;
            float sap = apx * apx + apy * apy + apz * apz;
            float d1 = apx * abx + apy * aby + apz * abz;
            float d2 = apx * acx + apy * acy + apz * acz;
            float t0 = __builtin_amdgcn_fmed3f(d1 * rsaa, 0.0f, 1.0f);
            float h0 = d1 + d1;
            float dab = sap - t0 * (h0 - t0 * saa);
            float t1 = __builtin_amdgcn_fmed3f(d2 * rscc, 0.0f, 1.0f);
            float dac = sap - t1 * ((d2 + d2) - t1 * scc);
            float e1 = (d2 - d1) + k1;
            float t2 = __builtin_amdgcn_fmed3f(e1 * rcbb, 0.0f, 1.0f);
            float bpp = (sap - h0) + saa;
            float dbc = bpp - t2 * ((e1 + e1) - t2 * cbb);
            float dmin = fminf(fminf(dab, dac), dbc);
            float vnum = scc * d1 - sab * d2;
            float wnum = saa * d2 - sab * d1;
            bool inside = (vnum >= 0.0f) & (wnum >= 0.0f) & ((vnum + wnum) <= det);
            float idist = sap - (vnum * d1 + wnum * d2) * rdet;
            float d = fmaxf(inside ? fminf(idist, dmin) : dmin, 0.0f);
            wcode |= (unsigned)dcode(d) << (8 * g);
            best[g] = fminf(best[g], d);
        }
        dstore32[f] = wcode;

        q0 = n0; q1 = n1; q2 = n2;
    }

    // ---------------- min reduction: shfl butterfly + 1 barrier --------------
#pragma unroll
    for (int m = 1; m < 64; m <<= 1) {
#pragma unroll
        for (int g = 0; g < GPTS; ++g)
            best[g] = fminf(best[g], __shfl_xor(best[g], m));
    }
    if (lane == 0) {
#pragma unroll
        for (int g = 0; g < GPTS; ++g) swmin[wid][g] = best[g];
    }
    __syncthreads();   // orders dstore32 writes + scnt=0 before pass 2a

    float Tg[GPTS]; int codeT[GPTS];
#pragma unroll
    for (int g = 0; g < GPTS; ++g) {
        float mn = swmin[0][g];
#pragma unroll
        for (int w = 1; w < NWAVE; ++w) mn = fminf(mn, swmin[w][g]);
        Tg[g] = mn + (1e-4f + 1e-2f * mn);   // proven band (R9-R17)
        codeT[g] = dcode(Tg[g]);
    }

    // ---------------- pass 2a: scan codes, compact candidates ----------------
    for (int f = tid; f < F; f += TPB) {
        unsigned w = dstore32[f];
#pragma unroll
        for (int g = 0; g < GPTS; ++g) {
            if ((int)((w >> (8 * g)) & 0xffu) <= codeT[g]) {
                unsigned idx = atomicAdd(&scnt, 1u);
                if (idx < QCAP) squeue[idx] = ((unsigned)g << 13) | (unsigned)f;
            }
        }
    }
    __syncthreads();
    unsigned total = scnt;

    float bestE[GPTS]; int bestI[GPTS];
#pragma unroll
    for (int g = 0; g < GPTS; ++g) { bestE[g] = INFINITY; bestI[g] = 0x7fffffff; }

    if (total <= QCAP) {
        // ---------------- pass 2b: dense exact evals over queue ----------------
        for (unsigned q = tid; q < total; q += TPB) {
            unsigned e = squeue[q];
            int g = (int)(e >> 13);
            int f = (int)(e & 0x1fffu);
            int i0 = faces[f * 3 + 0], i1 = faces[f * 3 + 1], i2 = faces[f * 3 + 2];
            const float* pa = verts + ((size_t)b * V + i0) * 3;
            const float* pbv = verts + ((size_t)b * V + i1) * 3;
            const float* pc = verts + ((size_t)b * V + i2) * 3;
            float de = tri_sqdist_exact(px[g], py[g], pz[g],
                                        pa[0], pa[1], pa[2],
                                        pbv[0], pbv[1], pbv[2],
                                        pc[0], pc[1], pc[2]);
            if (de < bestE[g] || (de == bestE[g] && f < bestI[g])) {
                bestE[g] = de; bestI[g] = f;
            }
        }
    } else {
        // ---------------- overflow fallback: in-branch rescan (proven) --------
        for (int f = tid; f < F; f += TPB) {
            unsigned w = dstore32[f];
            bool cg[GPTS]; bool any = false;
#pragma unroll
            for (int g = 0; g < GPTS; ++g) {
                cg[g] = (int)((w >> (8 * g)) & 0xffu) <= codeT[g];
                any = any || cg[g];
            }
            if (any) {
                int i0 = faces[f * 3 + 0], i1 = faces[f * 3 + 1], i2 = faces[f * 3 + 2];
                const float* pa = verts + ((size_t)b * V + i0) * 3;
                const float* pbv = verts + ((size_t)b * V + i1) * 3;
                const float* pc = verts + ((size_t)b * V + i2) * 3;
                float ax = pa[0], ay = pa[1], az = pa[2];
                float bx = pbv[0], by = pbv[1], bz = pbv[2];
                float cx = pc[0], cy = pc[1], cz = pc[2];
#pragma unroll
                for (int g = 0; g < GPTS; ++g) {
                    if (cg[g]) {
                        float de = tri_sqdist_exact(px[g], py[g], pz[g],
                                                    ax, ay, az, bx, by, bz, cx, cy, cz);
                        if (de < bestE[g]) { bestE[g] = de; bestI[g] = f; }
                    }
                }
            }
        }
    }

    // ---------------- argmin: paired 32-bit shfl butterfly + 1 barrier --------
#pragma unroll
    for (int m = 1; m < 64; m <<= 1) {
#pragma unroll
        for (int g = 0; g < GPTS; ++g) {
            float od = __shfl_xor(bestE[g], m);
            int   oi = __shfl_xor(bestI[g], m);
            if (od < bestE[g] || (od == bestE[g] && oi < bestI[g])) {
                bestE[g] = od; bestI[g] = oi;
            }
        }
    }
    if (lane == 0) {
#pragma unroll
        for (int g = 0; g < GPTS; ++g) { sargd[wid][g] = bestE[g]; sargi[wid][g] = bestI[g]; }
    }
    __syncthreads();

    // ---------------- final: merge waves + exact barycentric + GMO (mirror) --
    if (tid < GPTS) {
#pragma clang fp contract(off)
        int g = tid;
        float dmn = sargd[0][g]; int imn = sargi[0][g];
#pragma unroll
        for (int w = 1; w < NWAVE; ++w) {
            float dv = sargd[w][g]; int iv = sargi[w][g];
            if (dv < dmn || (dv == dmn && iv < imn)) { dmn = dv; imn = iv; }
        }
        int f = imn;
        int gp = gp0 + g;
        if (gp < npts) {
            int i0 = faces[f * 3 + 0], i1 = faces[f * 3 + 1], i2 = faces[f * 3 + 2];
            const float* pa = verts + ((size_t)b * V + i0) * 3;
            const float* pbv = verts + ((size_t)b * V + i1) * 3;
            const float* pc = verts + ((size_t)b * V + i2) * 3;
            float ax = pa[0], ay = pa[1], az = pa[2];
            float bx = pbv[0], by = pbv[1], bz = pbv[2];
            float cx = pc[0], cy = pc[1], cz = pc[2];
            float Px = px[g], Py = py[g], Pz = pz[g];
            float v1x = bx - ax, v1y = by - ay, v1z = bz - az;
            float v2x = cx - ax, v2y = cy - ay, v2z = cz - az;
            float nx = v1y * v2z - v1z * v2y;
            float ny = v1z * v2x - v1x * v2z;
            float nz = v1x * v2y - v1y * v2x;
            float nn = nx * nx + ny * ny + nz * nz;
            if (nn < EPS_BARY) nn = 1.0f;
            float wx = Px - ax, wy = Py - ay, wz = Pz - az;
            float c1x = v1y * wz - v1z * wy;
            float c1y = v1z * wx - v1x * wz;
            float c1z = v1x * wy - v1y * wx;
            float gamma = (c1x * nx + c1y * ny + c1z * nz) / nn;
            float c2x = wy * v2z - wz * v2y;
            float c2y = wz * v2x - wx * v2z;
            float c2z = wx * v2y - wy * v2x;
            float beta = (c2x * nx + c2y * ny + c2z * nz) / nn;
            float alpha = 1.0f - beta - gamma;
            float cpx = ax * alpha + bx * beta + cx * gamma;
            float cpy = ay * alpha + by * beta + cy * gamma;
            float cpz = az * alpha + bz * beta + cz * gamma;
            float dx = cpx - Px, dy = cpy - Py, dz = cpz - Pz;
            float sdist = dx * dx + dy * dy + dz * dz;
            float r = sqrtf(sdist / (1.0f + sdist) + EPS_GMO);
            robust_out[gp] = r;
        }
    }
}

// ---------------------------------------------------------------------------
// Kernel 3: deterministic fixed-order mean of N values -> out[0]
// ---------------------------------------------------------------------------
__global__ __launch_bounds__(RTPB) void reduce_mean_kernel(
    const float* __restrict__ vals, float* __restrict__ out, int N, float inv)
{
    __shared__ float s[RTPB];
    int tid = threadIdx.x;
    float acc = 0.0f;
    for (int i = tid; i < N; i += RTPB) acc += vals[i];
    s[tid] = acc;
    __syncthreads();
    for (int st = RTPB / 2; st > 0; st >>= 1) {
        if (tid < st) s[tid] += s[tid + st];
        __syncthreads();
    }
    if (tid == 0) out[0] = s[0] * inv;
}

// ---------------------------------------------------------------------------
extern "C" void kernel_launch(void* const* d_in, const int* in_sizes, int n_in,
                              void* d_out, int out_size, void* d_ws, size_t ws_size,
                              hipStream_t stream)
{
    const float* points = (const float*)d_in[0];
    const float* verts  = (const float*)d_in[1];
    const int*   faces  = (const int*)d_in[2];
    float* out = (float*)d_out;

    const int B = 2;  // fixed by the reference setup
    const int P = in_sizes[0] / (B * 3);
    const int V = in_sizes[1] / (B * 3);
    const int F = in_sizes[2] / 3;
    const int npts = B * P;

    // ws layout (507,904 B total -- proven in rounds 2/5/8-12/14-17):
    float* fdat   = (float*)d_ws;                    // B*F*12 floats
    float* robust = fdat + (size_t)B * F * FSTRIDE;  // npts floats

    int nBF = B * F;
    gather_fdat_kernel<<<(nBF + RTPB - 1) / RTPB, RTPB, 0, stream>>>(verts, faces, fdat, B, F, V);

    int nBlocks = (npts + GPTS - 1) / GPTS;          // 1024 blocks of 512 thr
    size_t dynLds = (size_t)F * sizeof(unsigned);    // 20,480 B
    p2s_main_kernel<<<nBlocks, TPB, dynLds, stream>>>(points, verts, faces, fdat, robust, P, V, F, npts);

    reduce_mean_kernel<<<1, RTPB, 0, stream>>>(robust, out, npts, 1.0f / (float)npts);
}

// Round 19
// 53.293 us; speedup vs baseline: 1.0241x; 1.0144x over previous
//
#include <hip/hip_runtime.h>
#include <math.h>

#define EPS_GMO  1e-16f
#define EPS_BARY 1e-16f
#define EPS_DIV  1e-12f
#define TPB  512
#define RTPB 256
#define NWAVE (TPB / 64)
#define GPTS 4
#define FSTRIDE 12
#define QCAP 2048

// ---------------------------------------------------------------------------
// Kernel 1: per-face constants: a(3), ab(3), ac(3), saa, sab, scc (12 floats).
// ---------------------------------------------------------------------------
__global__ void gather_fdat_kernel(const float* __restrict__ verts,
                                   const int* __restrict__ faces,
                                   float* __restrict__ fdat,
                                   int B, int F, int V)
{
    int i = blockIdx.x * blockDim.x + threadIdx.x;
    if (i >= B * F) return;
    int b = i / F;
    int f = i - b * F;
    int i0 = faces[f * 3 + 0], i1 = faces[f * 3 + 1], i2 = faces[f * 3 + 2];
    const float* pa = verts + ((size_t)b * V + i0) * 3;
    const float* pb = verts + ((size_t)b * V + i1) * 3;
    const float* pc = verts + ((size_t)b * V + i2) * 3;
    float ax = pa[0], ay = pa[1], az = pa[2];
    float abx = pb[0] - ax, aby = pb[1] - ay, abz = pb[2] - az;
    float acx = pc[0] - ax, acy = pc[1] - ay, acz = pc[2] - az;
    float saa = abx * abx + aby * aby + abz * abz;
    float sab = abx * acx + aby * acy + abz * acz;
    float scc = acx * acx + acy * acy + acz * acz;
    float* o = fdat + (size_t)i * FSTRIDE;
    o[0] = ax;  o[1] = ay;  o[2] = az;
    o[3] = abx; o[4] = aby; o[5] = abz;
    o[6] = acx; o[7] = acy; o[8] = acz;
    o[9] = saa; o[10] = sab; o[11] = scc;
}

// ---------------------------------------------------------------------------
// Exact squared point-triangle distance — BITWISE mirror of the reference
// (validated absmax 0.0 in 13 passing rounds). Used only on candidates.
// ---------------------------------------------------------------------------
__device__ float tri_sqdist_exact(float px, float py, float pz,
                                  float ax, float ay, float az,
                                  float bx, float by, float bz,
                                  float cx, float cy, float cz)
{
#pragma clang fp contract(off)
    float abx = bx - ax, aby = by - ay, abz = bz - az;
    float acx = cx - ax, acy = cy - ay, acz = cz - az;
    float apx = px - ax, apy = py - ay, apz = pz - az;
    float d1 = abx * apx + aby * apy + abz * apz;
    float d2 = acx * apx + acy * apy + acz * apz;
    float bpx = px - bx, bpy = py - by, bpz = pz - bz;
    float d3 = abx * bpx + aby * bpy + abz * bpz;
    float d4 = acx * bpx + acy * bpy + acz * bpz;
    float cpx_ = px - cx, cpy_ = py - cy, cpz_ = pz - cz;
    float d5 = abx * cpx_ + aby * cpy_ + abz * cpz_;
    float d6 = acx * cpx_ + acy * cpy_ + acz * cpz_;
    float va = d3 * d6 - d5 * d4;
    float vb = d5 * d2 - d1 * d6;
    float vc = d1 * d4 - d3 * d2;
    float t_ab = d1 / fmaxf(d1 - d3, EPS_DIV);
    float t_ac = d2 / fmaxf(d2 - d6, EPS_DIV);
    float t_bc = (d4 - d3) / fmaxf((d4 - d3) + (d5 - d6), EPS_DIV);
    float den = fmaxf(va + vb + vc, EPS_DIV);
    float v = vb / den;
    float w = vc / den;
    float qx = ax + v * abx + w * acx;
    float qy = ay + v * aby + w * acy;
    float qz = az + v * abz + w * acz;
    bool m_bc = (va <= 0.0f) && (d4 - d3 >= 0.0f) && (d5 - d6 >= 0.0f);
    bool m_ac = (vb <= 0.0f) && (d2 >= 0.0f) && (d6 <= 0.0f);
    bool m_ab = (vc <= 0.0f) && (d1 >= 0.0f) && (d3 <= 0.0f);
    bool m_a  = (d1 <= 0.0f) && (d2 <= 0.0f);
    bool m_b  = (d3 >= 0.0f) && (d4 <= d3);
    bool m_c  = (d6 >= 0.0f) && (d5 <= d6);
    if (m_bc) { qx = bx + t_bc * (cx - bx); qy = by + t_bc * (cy - by); qz = bz + t_bc * (cz - bz); }
    if (m_ac) { qx = ax + t_ac * acx;       qy = ay + t_ac * acy;       qz = az + t_ac * acz; }
    if (m_ab) { qx = ax + t_ab * abx;       qy = ay + t_ab * aby;       qz = az + t_ab * abz; }
    if (m_c)  { qx = cx; qy = cy; qz = cz; }
    if (m_b)  { qx = bx; qy = by; qz = bz; }
    if (m_a)  { qx = ax; qy = ay; qz = az; }
    float dx = px - qx, dy = py - qy, dz = pz - qz;
    return dx * dx + dy * dy + dz * dz;
}

// u8 code: monotone floor of d (exponent + 2 mantissa bits), so
// d <= T  ==>  code(d) <= code(T). Candidate set only inflates (~1.19x).
__device__ __forceinline__ int dcode(float d)
{
    unsigned raw = __float_as_uint(d) >> 21;
    int c = (int)raw - 380;
    return c < 0 ? 0 : (c > 255 ? 255 : c);
}

// ---------------------------------------------------------------------------
// Main kernel (champion config, R16): LDS u8-code store + queue compaction,
// shfl-butterfly reductions (3 barriers), TPB=512 / GPTS=4.
// ---------------------------------------------------------------------------
__global__ __launch_bounds__(TPB) void p2s_main_kernel(
    const float* __restrict__ points,
    const float* __restrict__ verts,
    const int* __restrict__ faces,
    const float* __restrict__ fdat,
    float* __restrict__ robust_out,
    int P, int V, int F, int npts)
{
    extern __shared__ unsigned dstore32[];       // [F] 4x u8 codes per word
    __shared__ float swmin[NWAVE][GPTS];
    __shared__ float sargd[NWAVE][GPTS];
    __shared__ int   sargi[NWAVE][GPTS];
    __shared__ unsigned squeue[QCAP];
    __shared__ unsigned scnt;

    const int tid  = threadIdx.x;
    const int lane = tid & 63;
    const int wid  = tid >> 6;
    const int gp0  = blockIdx.x * GPTS;
    const int b    = gp0 / P;   // P % GPTS == 0, block never straddles batches

    if (tid == 0) scnt = 0;

    float px[GPTS], py[GPTS], pz[GPTS];
#pragma unroll
    for (int g = 0; g < GPTS; ++g) {
        int gp = gp0 + g; if (gp >= npts) gp = npts - 1;
        const float* pp = points + (size_t)gp * 3;
        px[g] = pp[0]; py[g] = pp[1]; pz[g] = pp[2];
    }

    const float* fb = fdat + (size_t)b * F * FSTRIDE;

    // ---------------- pass 1: cheap exact screen ----------------
    float best[GPTS];
#pragma unroll
    for (int g = 0; g < GPTS; ++g) best[g] = INFINITY;

    for (int f = tid; f < F; f += TPB) {
        const float* fd = fb + (size_t)f * FSTRIDE;
        float4 q0 = *(const float4*)(fd + 0);
        float4 q1 = *(const float4*)(fd + 4);
        float4 q2 = *(const float4*)(fd + 8);
        float ax = q0.x, ay = q0.y, az = q0.z;
        float abx = q0.w, aby = q1.x, abz = q1.y;
        float acx = q1.z, acy = q1.w, acz = q2.x;
        float saa = q2.y, sab = q2.z, scc = q2.w;
        float cbb = saa - 2.0f * sab + scc;
        float det = saa * scc - sab * sab;
        float rsaa = __builtin_amdgcn_rcpf(fmaxf(saa, 1e-30f));
        float rscc = __builtin_amdgcn_rcpf(fmaxf(scc, 1e-30f));
        float rcbb = __builtin_amdgcn_rcpf(fmaxf(cbb, 1e-30f));
        float rdet = __builtin_amdgcn_rcpf(fmaxf(det, 1e-30f));
        float k1 = saa - sab;
        unsigned wcode = 0;
#pragma unroll
        for (int g = 0; g < GPTS; ++g) {
            float apx = px[g] - ax, apy = py[g] - ay, apz = pz[g] - az;
            float sap = apx * apx + apy * apy + apz * apz;
            float d1 = apx * abx + apy * aby + apz * abz;
            float d2 = apx * acx + apy * acy + apz * acz;
            float t0 = __builtin_amdgcn_fmed3f(d1 * rsaa, 0.0f, 1.0f);
            float h0 = d1 + d1;
            float dab = sap - t0 * (h0 - t0 * saa);
            float t1 = __builtin_amdgcn_fmed3f(d2 * rscc, 0.0f, 1.0f);
            float dac = sap - t1 * ((d2 + d2) - t1 * scc);
            float e1 = (d2 - d1) + k1;
            float t2 = __builtin_amdgcn_fmed3f(e1 * rcbb, 0.0f, 1.0f);
            float bpp = (sap - h0) + saa;
            float dbc = bpp - t2 * ((e1 + e1) - t2 * cbb);
            float dmin = fminf(fminf(dab, dac), dbc);
            float vnum = scc * d1 - sab * d2;
            float wnum = saa * d2 - sab * d1;
            bool inside = (vnum >= 0.0f) & (wnum >= 0.0f) & ((vnum + wnum) <= det);
            float idist = sap - (vnum * d1 + wnum * d2) * rdet;
            float d = fmaxf(inside ? fminf(idist, dmin) : dmin, 0.0f);
            wcode |= (unsigned)dcode(d) << (8 * g);
            best[g] = fminf(best[g], d);
        }
        dstore32[f] = wcode;
    }

    // ---------------- min reduction: shfl butterfly + 1 barrier --------------
#pragma unroll
    for (int m = 1; m < 64; m <<= 1) {
#pragma unroll
        for (int g = 0; g < GPTS; ++g)
            best[g] = fminf(best[g], __shfl_xor(best[g], m));
    }
    if (lane == 0) {
#pragma unroll
        for (int g = 0; g < GPTS; ++g) swmin[wid][g] = best[g];
    }
    __syncthreads();   // orders dstore32 writes + scnt=0 before pass 2a

    float Tg[GPTS]; int codeT[GPTS];
#pragma unroll
    for (int g = 0; g < GPTS; ++g) {
        float mn = swmin[0][g];
#pragma unroll
        for (int w = 1; w < NWAVE; ++w) mn = fminf(mn, swmin[w][g]);
        Tg[g] = mn + (1e-4f + 1e-2f * mn);   // proven band (R9-R18)
        codeT[g] = dcode(Tg[g]);
    }

    // ---------------- pass 2a: scan codes, compact candidates ----------------
    for (int f = tid; f < F; f += TPB) {
        unsigned w = dstore32[f];
#pragma unroll
        for (int g = 0; g < GPTS; ++g) {
            if ((int)((w >> (8 * g)) & 0xffu) <= codeT[g]) {
                unsigned idx = atomicAdd(&scnt, 1u);
                if (idx < QCAP) squeue[idx] = ((unsigned)g << 13) | (unsigned)f;
            }
        }
    }
    __syncthreads();
    unsigned total = scnt;

    float bestE[GPTS]; int bestI[GPTS];
#pragma unroll
    for (int g = 0; g < GPTS; ++g) { bestE[g] = INFINITY; bestI[g] = 0x7fffffff; }

    if (total <= QCAP) {
        // ---------------- pass 2b: dense exact evals over queue ----------------
        for (unsigned q = tid; q < total; q += TPB) {
            unsigned e = squeue[q];
            int g = (int)(e >> 13);
            int f = (int)(e & 0x1fffu);
            int i0 = faces[f * 3 + 0], i1 = faces[f * 3 + 1], i2 = faces[f * 3 + 2];
            const float* pa = verts + ((size_t)b * V + i0) * 3;
            const float* pbv = verts + ((size_t)b * V + i1) * 3;
            const float* pc = verts + ((size_t)b * V + i2) * 3;
            float de = tri_sqdist_exact(px[g], py[g], pz[g],
                                        pa[0], pa[1], pa[2],
                                        pbv[0], pbv[1], pbv[2],
                                        pc[0], pc[1], pc[2]);
            if (de < bestE[g] || (de == bestE[g] && f < bestI[g])) {
                bestE[g] = de; bestI[g] = f;
            }
        }
    } else {
        // ---------------- overflow fallback: in-branch rescan (proven) --------
        for (int f = tid; f < F; f += TPB) {
            unsigned w = dstore32[f];
            bool cg[GPTS]; bool any = false;
#pragma unroll
            for (int g = 0; g < GPTS; ++g) {
                cg[g] = (int)((w >> (8 * g)) & 0xffu) <= codeT[g];
                any = any || cg[g];
            }
            if (any) {
                int i0 = faces[f * 3 + 0], i1 = faces[f * 3 + 1], i2 = faces[f * 3 + 2];
                const float* pa = verts + ((size_t)b * V + i0) * 3;
                const float* pbv = verts + ((size_t)b * V + i1) * 3;
                const float* pc = verts + ((size_t)b * V + i2) * 3;
                float ax = pa[0], ay = pa[1], az = pa[2];
                float bx = pbv[0], by = pbv[1], bz = pbv[2];
                float cx = pc[0], cy = pc[1], cz = pc[2];
#pragma unroll
                for (int g = 0; g < GPTS; ++g) {
                    if (cg[g]) {
                        float de = tri_sqdist_exact(px[g], py[g], pz[g],
                                                    ax, ay, az, bx, by, bz, cx, cy, cz);
                        if (de < bestE[g]) { bestE[g] = de; bestI[g] = f; }
                    }
                }
            }
        }
    }

    // ---------------- argmin: paired 32-bit shfl butterfly + 1 barrier --------
#pragma unroll
    for (int m = 1; m < 64; m <<= 1) {
#pragma unroll
        for (int g = 0; g < GPTS; ++g) {
            float od = __shfl_xor(bestE[g], m);
            int   oi = __shfl_xor(bestI[g], m);
            if (od < bestE[g] || (od == bestE[g] && oi < bestI[g])) {
                bestE[g] = od; bestI[g] = oi;
            }
        }
    }
    if (lane == 0) {
#pragma unroll
        for (int g = 0; g < GPTS; ++g) { sargd[wid][g] = bestE[g]; sargi[wid][g] = bestI[g]; }
    }
    __syncthreads();

    // ---------------- final: merge waves + exact barycentric + GMO (mirror) --
    if (tid < GPTS) {
#pragma clang fp contract(off)
        int g = tid;
        float dmn = sargd[0][g]; int imn = sargi[0][g];
#pragma unroll
        for (int w = 1; w < NWAVE; ++w) {
            float dv = sargd[w][g]; int iv = sargi[w][g];
            if (dv < dmn || (dv == dmn && iv < imn)) { dmn = dv; imn = iv; }
        }
        int f = imn;
        int gp = gp0 + g;
        if (gp < npts) {
            int i0 = faces[f * 3 + 0], i1 = faces[f * 3 + 1], i2 = faces[f * 3 + 2];
            const float* pa = verts + ((size_t)b * V + i0) * 3;
            const float* pbv = verts + ((size_t)b * V + i1) * 3;
            const float* pc = verts + ((size_t)b * V + i2) * 3;
            float ax = pa[0], ay = pa[1], az = pa[2];
            float bx = pbv[0], by = pbv[1], bz = pbv[2];
            float cx = pc[0], cy = pc[1], cz = pc[2];
            float Px = px[g], Py = py[g], Pz = pz[g];
            float v1x = bx - ax, v1y = by - ay, v1z = bz - az;
            float v2x = cx - ax, v2y = cy - ay, v2z = cz - az;
            float nx = v1y * v2z - v1z * v2y;
            float ny = v1z * v2x - v1x * v2z;
            float nz = v1x * v2y - v1y * v2x;
            float nn = nx * nx + ny * ny + nz * nz;
            if (nn < EPS_BARY) nn = 1.0f;
            float wx = Px - ax, wy = Py - ay, wz = Pz - az;
            float c1x = v1y * wz - v1z * wy;
            float c1y = v1z * wx - v1x * wz;
            float c1z = v1x * wy - v1y * wx;
            float gamma = (c1x * nx + c1y * ny + c1z * nz) / nn;
            float c2x = wy * v2z - wz * v2y;
            float c2y = wz * v2x - wx * v2z;
            float c2z = wx * v2y - wy * v2x;
            float beta = (c2x * nx + c2y * ny + c2z * nz) / nn;
            float alpha = 1.0f - beta - gamma;
            float cpx = ax * alpha + bx * beta + cx * gamma;
            float cpy = ay * alpha + by * beta + cy * gamma;
            float cpz = az * alpha + bz * beta + cz * gamma;
            float dx = cpx - Px, dy = cpy - Py, dz = cpz - Pz;
            float sdist = dx * dx + dy * dy + dz * dz;
            float r = sqrtf(sdist / (1.0f + sdist) + EPS_GMO);
            robust_out[gp] = r;
        }
    }
}

// ---------------------------------------------------------------------------
// Kernel 3: deterministic fixed-order mean of N values -> out[0]
// ---------------------------------------------------------------------------
__global__ __launch_bounds__(RTPB) void reduce_mean_kernel(
    const float* __restrict__ vals, float* __restrict__ out, int N, float inv)
{
    __shared__ float s[RTPB];
    int tid = threadIdx.x;
    float acc = 0.0f;
    for (int i = tid; i < N; i += RTPB) acc += vals[i];
    s[tid] = acc;
    __syncthreads();
    for (int st = RTPB / 2; st > 0; st >>= 1) {
        if (tid < st) s[tid] += s[tid + st];
        __syncthreads();
    }
    if (tid == 0) out[0] = s[0] * inv;
}

// ---------------------------------------------------------------------------
extern "C" void kernel_launch(void* const* d_in, const int* in_sizes, int n_in,
                              void* d_out, int out_size, void* d_ws, size_t ws_size,
                              hipStream_t stream)
{
    const float* points = (const float*)d_in[0];
    const float* verts  = (const float*)d_in[1];
    const int*   faces  = (const int*)d_in[2];
    float* out = (float*)d_out;

    const int B = 2;  // fixed by the reference setup
    const int P = in_sizes[0] / (B * 3);
    const int V = in_sizes[1] / (B * 3);
    const int F = in_sizes[2] / 3;
    const int npts = B * P;

    // ws layout (507,904 B total -- proven across 13 passing rounds):
    float* fdat   = (float*)d_ws;                    // B*F*12 floats
    float* robust = fdat + (size_t)B * F * FSTRIDE;  // npts floats

    int nBF = B * F;
    gather_fdat_kernel<<<(nBF + RTPB - 1) / RTPB, RTPB, 0, stream>>>(verts, faces, fdat, B, F, V);

    int nBlocks = (npts + GPTS - 1) / GPTS;          // 1024 blocks of 512 thr
    size_t dynLds = (size_t)F * sizeof(unsigned);    // 20,480 B
    p2s_main_kernel<<<nBlocks, TPB, dynLds, stream>>>(points, verts, faces, fdat, robust, P, V, F, npts);

    reduce_mean_kernel<<<1, RTPB, 0, stream>>>(robust, out, npts, 1.0f / (float)npts);
}